// Round 1
// baseline (4503.517 us; speedup 1.0000x reference)
//
#include <hip/hip_runtime.h>
#include <hip/hip_bf16.h>

// Problem constants (fixed by the reference)
#define BATCH 4
#define TSEQ 2048
#define DM 1024
#define NH 16
#define DH 64
#define MROWS (BATCH * TSEQ)  // 8192

// ---------- type helpers ----------
__device__ __forceinline__ float ldf(const float* p) { return *p; }
__device__ __forceinline__ float ldf(const __hip_bfloat16* p) { return __bfloat162float(*p); }
__device__ __forceinline__ void stf(float* p, float v) { *p = v; }
__device__ __forceinline__ void stf(__hip_bfloat16* p, float v) { *p = __float2bfloat16(v); }

// ---------- generic fp32-compute tiled GEMM: C(MxN) = A(MxK) @ B(KxN) ----------
// BM=BN=64, BK=16, 256 threads, each thread 4x4 micro-tile.
#define BM 64
#define BN 64
#define BK 16

template <typename TA, typename TC>
__global__ __launch_bounds__(256) void gemm_kernel(const TA* __restrict__ A,
                                                   const float* __restrict__ B,
                                                   TC* __restrict__ C,
                                                   int M, int N, int K) {
    __shared__ float As[BK][BM + 1];
    __shared__ float Bs[BK][BN + 1];
    const int tid = threadIdx.x;
    const int tr = tid / 16;  // 0..15 row group
    const int tc = tid % 16;  // 0..15 col group
    const int rowBase = blockIdx.y * BM;
    const int colBase = blockIdx.x * BN;

    float acc[4][4];
#pragma unroll
    for (int m = 0; m < 4; ++m)
#pragma unroll
        for (int n = 0; n < 4; ++n) acc[m][n] = 0.f;

    for (int k0 = 0; k0 < K; k0 += BK) {
        // load A tile: BM x BK (store transposed As[c][r])
#pragma unroll
        for (int i = tid; i < BM * BK; i += 256) {
            int r = i / BK, c = i % BK;
            As[c][r] = ldf(&A[(size_t)(rowBase + r) * K + k0 + c]);
        }
        // load B tile: BK x BN
#pragma unroll
        for (int i = tid; i < BK * BN; i += 256) {
            int r = i / BN, c = i % BN;
            Bs[r][c] = B[(size_t)(k0 + r) * N + colBase + c];
        }
        __syncthreads();
#pragma unroll
        for (int kk = 0; kk < BK; ++kk) {
            float a[4], b[4];
#pragma unroll
            for (int m = 0; m < 4; ++m) a[m] = As[kk][tr * 4 + m];
#pragma unroll
            for (int n = 0; n < 4; ++n) b[n] = Bs[kk][tc * 4 + n];
#pragma unroll
            for (int m = 0; m < 4; ++m)
#pragma unroll
                for (int n = 0; n < 4; ++n) acc[m][n] += a[m] * b[n];
        }
        __syncthreads();
    }
#pragma unroll
    for (int m = 0; m < 4; ++m)
#pragma unroll
        for (int n = 0; n < 4; ++n)
            stf(&C[(size_t)(rowBase + tr * 4 + m) * N + colBase + tc * 4 + n], acc[m][n]);
}

// ---------- beta = sigmoid(x @ Wbeta + b_beta), Wbeta (1024x16) ----------
// 256 threads = 16 rows x 16 heads per block.
__global__ __launch_bounds__(256) void beta_kernel(const float* __restrict__ x,
                                                   const float* __restrict__ Wb,
                                                   const float* __restrict__ bb,
                                                   float* __restrict__ beta) {
    const int tid = threadIdx.x;
    const int h = tid % NH;
    const int rl = tid / NH;
    const int row = blockIdx.x * 16 + rl;
    const float* xr = x + (size_t)row * DM;
    float acc = 0.f;
#pragma unroll 8
    for (int k = 0; k < DM; ++k) acc += xr[k] * Wb[k * NH + h];
    acc += bb[h];
    beta[row * NH + h] = 1.f / (1.f + __expf(-acc));
}

// ---------- sequential DeltaNet scan ----------
// One block (1 wave, 64 threads) per (b,h). Thread i owns row i of W (64 VGPRs).
// k is L2-normalized here (full-wave shfl reduce over exactly DH=64 lanes).
template <typename TS>
__global__ __launch_bounds__(64) void scan_kernel(const TS* __restrict__ Q,
                                                  const TS* __restrict__ K,
                                                  const TS* __restrict__ V,
                                                  const float* __restrict__ beta,
                                                  float* __restrict__ O) {
    const int bh = blockIdx.x;
    const int b = bh >> 4;
    const int h = bh & 15;
    const int lane = threadIdx.x;

    float Wrow[64];
#pragma unroll
    for (int j = 0; j < 64; ++j) Wrow[j] = 0.f;

    __shared__ float sk[64];
    __shared__ float sq[64];

    size_t base = ((size_t)b * TSEQ) * (NH * DH) + h * DH + lane;
    int brow = b * TSEQ;  // beta row index base

    for (int t = 0; t < TSEQ; ++t, base += NH * DH) {
        float k = ldf(&K[base]);
        float q = ldf(&Q[base]);
        float v = ldf(&V[base]);
        float be = beta[(size_t)(brow + t) * NH + h];

        // L2 norm of k across the 64 lanes (== head dim)
        float ss = k * k;
#pragma unroll
        for (int off = 32; off > 0; off >>= 1) ss += __shfl_xor(ss, off);
        k = k / fmaxf(sqrtf(ss), 1e-12f);

        sk[lane] = k;
        sq[lane] = q;
        __syncthreads();

        // pred_i = W[i][:] . k  (4 partial accumulators to break FMA chain)
        float p0 = 0.f, p1 = 0.f, p2 = 0.f, p3 = 0.f;
#pragma unroll
        for (int j = 0; j < 64; j += 4) {
            p0 += Wrow[j + 0] * sk[j + 0];
            p1 += Wrow[j + 1] * sk[j + 1];
            p2 += Wrow[j + 2] * sk[j + 2];
            p3 += Wrow[j + 3] * sk[j + 3];
        }
        const float bei = be * (v - ((p0 + p1) + (p2 + p3)));

        // W[i][:] += bei * k ;  o_i = W_new[i][:] . q
        float o0 = 0.f, o1 = 0.f, o2 = 0.f, o3 = 0.f;
#pragma unroll
        for (int j = 0; j < 64; j += 4) {
            Wrow[j + 0] += bei * sk[j + 0]; o0 += Wrow[j + 0] * sq[j + 0];
            Wrow[j + 1] += bei * sk[j + 1]; o1 += Wrow[j + 1] * sq[j + 1];
            Wrow[j + 2] += bei * sk[j + 2]; o2 += Wrow[j + 2] * sq[j + 2];
            Wrow[j + 3] += bei * sk[j + 3]; o3 += Wrow[j + 3] * sq[j + 3];
        }
        O[base] = (o0 + o1) + (o2 + o3);
        __syncthreads();  // protect sk/sq before next iteration overwrites
    }
}

// ---------- launch ----------
extern "C" void kernel_launch(void* const* d_in, const int* in_sizes, int n_in,
                              void* d_out, int out_size, void* d_ws, size_t ws_size,
                              hipStream_t stream) {
    const float* x     = (const float*)d_in[0];
    const float* Wq    = (const float*)d_in[1];
    const float* Wk    = (const float*)d_in[2];
    const float* Wv    = (const float*)d_in[3];
    const float* Wbeta = (const float*)d_in[4];
    const float* bbeta = (const float*)d_in[5];
    const float* Wout  = (const float*)d_in[6];
    float* out = (float*)d_out;

    const size_t projElems = (size_t)MROWS * DM;          // 8192*1024
    const size_t betaBytes = (size_t)MROWS * NH * 4;      // 512 KiB
    const size_t f32Bytes  = projElems * 4;               // 32 MiB
    const size_t bf16Bytes = projElems * 2;               // 16 MiB
    const size_t need_f32  = 3 * f32Bytes + betaBytes + f32Bytes;  // Q,K,V,beta,O

    char* ws = (char*)d_ws;
    size_t off = 0;
    auto alloc = [&](size_t bytes) {
        char* p = ws + off;
        off += (bytes + 255) & ~(size_t)255;
        return (void*)p;
    };

    const dim3 gemmGrid(DM / BN, MROWS / BM);  // (16, 128)
    const dim3 gemmBlock(256);

    if (ws_size >= need_f32) {
        // fp32 storage path
        float* Qf = (float*)alloc(f32Bytes);
        float* Kf = (float*)alloc(f32Bytes);
        float* Vf = (float*)alloc(f32Bytes);
        float* betaf = (float*)alloc(betaBytes);
        float* Of = (float*)alloc(f32Bytes);

        gemm_kernel<float, float><<<gemmGrid, gemmBlock, 0, stream>>>(x, Wq, Qf, MROWS, DM, DM);
        gemm_kernel<float, float><<<gemmGrid, gemmBlock, 0, stream>>>(x, Wk, Kf, MROWS, DM, DM);
        gemm_kernel<float, float><<<gemmGrid, gemmBlock, 0, stream>>>(x, Wv, Vf, MROWS, DM, DM);
        beta_kernel<<<dim3(MROWS / 16), dim3(256), 0, stream>>>(x, Wbeta, bbeta, betaf);
        scan_kernel<float><<<dim3(BATCH * NH), dim3(64), 0, stream>>>(Qf, Kf, Vf, betaf, Of);
        gemm_kernel<float, float><<<gemmGrid, gemmBlock, 0, stream>>>(Of, Wout, out, MROWS, DM, DM);
    } else {
        // bf16 storage fallback (smaller workspace)
        __hip_bfloat16* Qh = (__hip_bfloat16*)alloc(bf16Bytes);
        __hip_bfloat16* Kh = (__hip_bfloat16*)alloc(bf16Bytes);
        __hip_bfloat16* Vh = (__hip_bfloat16*)alloc(bf16Bytes);
        float* betaf = (float*)alloc(betaBytes);
        float* Of = (float*)alloc(f32Bytes);

        gemm_kernel<float, __hip_bfloat16><<<gemmGrid, gemmBlock, 0, stream>>>(x, Wq, Qh, MROWS, DM, DM);
        gemm_kernel<float, __hip_bfloat16><<<gemmGrid, gemmBlock, 0, stream>>>(x, Wk, Kh, MROWS, DM, DM);
        gemm_kernel<float, __hip_bfloat16><<<gemmGrid, gemmBlock, 0, stream>>>(x, Wv, Vh, MROWS, DM, DM);
        beta_kernel<<<dim3(MROWS / 16), dim3(256), 0, stream>>>(x, Wbeta, bbeta, betaf);
        scan_kernel<__hip_bfloat16><<<dim3(BATCH * NH), dim3(64), 0, stream>>>(Qh, Kh, Vh, betaf, Of);
        gemm_kernel<float, float><<<gemmGrid, gemmBlock, 0, stream>>>(Of, Wout, out, MROWS, DM, DM);
    }
}